// Round 6
// baseline (222.570 us; speedup 1.0000x reference)
//
#include <hip/hip_runtime.h>
#include <hip/hip_bf16.h>
#include <hip/hip_cooperative_groups.h>

namespace cg = cooperative_groups;

// TextualKnowledgeInjector  B=64 T=256 F=40 D=768 H=256
// Single cooperative launch:
//  phase A: blocks 0..55   GEMM1 EWt[h][c] = W x E_compact^T (K=768, compacted avail pairs)
//           blocks 56..511 per-row S-bit bytes (compacted) + 1/cnt   (36 rows/block)
//  grid.sync()
//  phase B: all 512 blocks GEMM2 out = S(16384xK) x EWt^T(Kx256), K = ceil(npav/64)*64

#define FF 40
#define DD 768
#define HH 256
#define NPADJ 896      // EWt column stride
#define NPREAL 780
#define NROWS 16384
#define SBS 112        // S-byte stride per row
#define G1B 56         // 4 h-tiles x 14 c-tiles
#define GRID 512
#define MROWS 36       // mask rows per block (456 blocks cover 16384)

typedef short s8v __attribute__((ext_vector_type(8)));
typedef float f4v __attribute__((ext_vector_type(4)));
typedef unsigned short u16;
typedef unsigned long long u64;

__device__ __forceinline__ void gload16(const void* g, void* l) {
    __builtin_amdgcn_global_load_lds(
        (const __attribute__((address_space(1))) unsigned int*)g,
        (__attribute__((address_space(3))) unsigned int*)l, 16, 0, 0);
}
__device__ __forceinline__ u16 f2b(float f) {
    __hip_bfloat16 h = __float2bfloat16(f);
    return *(u16*)&h;
}
__device__ __forceinline__ unsigned pk2(float x, float y) {
    return (unsigned)f2b(x) | ((unsigned)f2b(y) << 16);
}
__device__ __forceinline__ void pair_ij(int p, int& i, int& j) {  // p < 780
    i = 0;
    int base = 0;
    while (base + (FF - 1 - i) <= p) { base += FF - 1 - i; ++i; }
    j = i + 1 + (p - base);
}

__global__ __launch_bounds__(256) void k_all(const int* __restrict__ smg,
                                             const float* __restrict__ E,
                                             const int* __restrict__ pa,
                                             const float* __restrict__ W,
                                             u16* __restrict__ EWt,
                                             unsigned char* __restrict__ sbytes,
                                             float* __restrict__ cntrcp,
                                             const float* __restrict__ bias,
                                             float* __restrict__ out) {
    __shared__ __align__(16) char SM[44032];  // phase-overlaid arena
    __shared__ int npavSh;
    int tid = threadIdx.x, lane = tid & 63, wid = tid >> 6;
    int bx = blockIdx.x;

    // ================= phase A =================
    if (bx < G1B) {
        // ---- GEMM1: 64x64 tile over (h, compact-pair), K=768, BK=64 ----
        char* As = SM;                       // 2 x 8192
        char* Bs = SM + 16384;               // 2 x 8192
        int* erowSh = (int*)(SM + 32768);    // 64 ints
        int bxx = bx / 14, by = bx % 14;
        int r0 = bxx * 64, c0 = by * 64;
        int wr = wid >> 1, wc = wid & 1;

        if (tid < 64) erowSh[tid] = 0;       // pads -> E row 0 (finite; S=0 masks)
        __syncthreads();
        if (wid == 0) {  // wave-0 compaction scan: 13 chunks of 64 over 780 pairs
            int base = 0;
            for (int c = 0; c < 13; ++c) {
                int p = c * 64 + lane;
                bool av = false;
                int i = 0, j = 0;
                if (p < NPREAL) { pair_ij(p, i, j); av = pa[i * FF + j] != 0; }
                u64 bal = __ballot(av);
                if (av) {
                    int cix = base + __popcll(bal & ((1ull << lane) - 1));
                    if (cix >= c0 && cix < c0 + 64) erowSh[cix - c0] = i * FF + j;
                }
                base += __popcll(bal);
            }
            if (lane == 0) npavSh = base;
        }
        __syncthreads();
        int npad64 = (npavSh + 63) & ~63;
        if (c0 < npad64) {   // inactive compact tiles skip (uniform) — NO return (coop!)
            int sOff[4];
            const float* aSrc[4];
            const float* bSrc[4];
#pragma unroll
            for (int r4 = 0; r4 < 4; ++r4) {
                int slot = tid + 256 * r4;
                int row = slot >> 4, kq = slot & 15;
                sOff[r4] = (row * 128 + kq * 8) ^ ((row & 7) << 4);
                aSrc[r4] = W + (size_t)(r0 + row) * DD + kq * 4;
                bSrc[r4] = E + (size_t)erowSh[row] * DD + kq * 4;
            }
            f4v acc[2][2];
#pragma unroll
            for (int m = 0; m < 2; ++m)
#pragma unroll
                for (int n = 0; n < 2; ++n) acc[m][n] = (f4v)0.0f;

            float4 ra[4], rb[4];
#pragma unroll
            for (int r4 = 0; r4 < 4; ++r4) { ra[r4] = *(const float4*)aSrc[r4]; rb[r4] = *(const float4*)bSrc[r4]; }
#pragma unroll
            for (int r4 = 0; r4 < 4; ++r4) {
                *(uint2*)(As + sOff[r4]) = make_uint2(pk2(ra[r4].x, ra[r4].y), pk2(ra[r4].z, ra[r4].w));
                *(uint2*)(Bs + sOff[r4]) = make_uint2(pk2(rb[r4].x, rb[r4].y), pk2(rb[r4].z, rb[r4].w));
            }
            __syncthreads();

            const int NT1 = DD / 64;  // 12
            for (int t = 0; t < NT1; ++t) {
                int cur = t & 1;
                if (t + 1 < NT1) {
                    int kb = (t + 1) * 64;
#pragma unroll
                    for (int r4 = 0; r4 < 4; ++r4) {
                        ra[r4] = *(const float4*)(aSrc[r4] + kb);
                        rb[r4] = *(const float4*)(bSrc[r4] + kb);
                    }
                }
                int kg16 = (lane >> 4) * 16;
#pragma unroll
                for (int ks = 0; ks < 2; ++ks) {
                    s8v a[2], b[2];
#pragma unroll
                    for (int m = 0; m < 2; ++m) {
                        int row = wr * 32 + m * 16 + (lane & 15);
                        a[m] = *(const s8v*)(As + cur * 8192 + ((row * 128 + ks * 64 + kg16) ^ ((row & 7) << 4)));
                    }
#pragma unroll
                    for (int n = 0; n < 2; ++n) {
                        int row = wc * 32 + n * 16 + (lane & 15);
                        b[n] = *(const s8v*)(Bs + cur * 8192 + ((row * 128 + ks * 64 + kg16) ^ ((row & 7) << 4)));
                    }
#pragma unroll
                    for (int m = 0; m < 2; ++m)
#pragma unroll
                        for (int n = 0; n < 2; ++n)
                            acc[m][n] = __builtin_amdgcn_mfma_f32_16x16x32_bf16(a[m], b[n], acc[m][n], 0, 0, 0);
                }
                if (t + 1 < NT1) {
                    int nb = (cur ^ 1) * 8192;
#pragma unroll
                    for (int r4 = 0; r4 < 4; ++r4) {
                        *(uint2*)(As + nb + sOff[r4]) = make_uint2(pk2(ra[r4].x, ra[r4].y), pk2(ra[r4].z, ra[r4].w));
                        *(uint2*)(Bs + nb + sOff[r4]) = make_uint2(pk2(rb[r4].x, rb[r4].y), pk2(rb[r4].z, rb[r4].w));
                    }
                }
                __syncthreads();
            }
#pragma unroll
            for (int m = 0; m < 2; ++m)
#pragma unroll
                for (int n = 0; n < 2; ++n) {
                    int colp = c0 + wc * 32 + n * 16 + (lane & 15);
#pragma unroll
                    for (int r4 = 0; r4 < 4; ++r4) {
                        int rowh = r0 + wr * 32 + m * 16 + (lane >> 4) * 4 + r4;
                        EWt[(size_t)rowh * NPADJ + colp] = f2b(acc[m][n][r4]);
                    }
                }
        }
    } else {
        // ---- mask: 36 rows per block; compacted pair masks in LDS ----
        u64* pmT = (u64*)SM;  // [8][SBS] flat: pmT[e*SBS+b]
#pragma unroll
        for (int rep = 0; rep < 4; ++rep) {
            int p = rep * 256 + tid;
            if (p < 896) pmT[(p & 7) * SBS + (p >> 3)] = ~0ull;  // never satisfied
        }
        __syncthreads();
        if (wid == 0) {  // wave-0 compaction scan (same order as gemm1 blocks)
            int base = 0;
            for (int c = 0; c < 13; ++c) {
                int p = c * 64 + lane;
                bool av = false;
                int i = 0, j = 0;
                if (p < NPREAL) { pair_ij(p, i, j); av = pa[i * FF + j] != 0; }
                u64 bal = __ballot(av);
                if (av) {
                    int cix = base + __popcll(bal & ((1ull << lane) - 1));
                    pmT[(cix & 7) * SBS + (cix >> 3)] = (1ull << i) | (1ull << j);
                }
                base += __popcll(bal);
            }
            if (lane == 0) npavSh = base;
        }
        __syncthreads();
        int r0m = (bx - G1B) * MROWS + wid * (MROWS / 4);
        for (int rr = 0; rr < MROWS / 4; ++rr) {
            int row = r0m + rr;
            if (row < NROWS) {
                int v = (lane < FF) ? smg[(size_t)row * FF + lane] : 0;
                u64 mask = __ballot(v != 0);
                int c = 0;
#pragma unroll
                for (int rep = 0; rep < 2; ++rep) {
                    int b = lane + rep * 64;
                    if (b < SBS) {
                        unsigned bits = 0;
#pragma unroll
                        for (int e = 0; e < 8; ++e) {
                            u64 q = pmT[e * SBS + b];
                            bits |= ((mask & q) == q) ? (1u << e) : 0u;
                        }
                        sbytes[(size_t)row * SBS + b] = (unsigned char)bits;
                        c += __popc(bits);
                    }
                }
#pragma unroll
                for (int o = 32; o; o >>= 1) c += __shfl_xor(c, o, 64);
                if (lane == 0) cntrcp[row] = 1.0f / (float)(c > 0 ? c : 1);
            }
        }
    }

    // ================= grid barrier =================
    __threadfence();          // device-scope release of EWt/sbytes/cntrcp
    cg::this_grid().sync();   // includes block sync; LDS arena reusable after

    // ================= phase B: GEMM2 =================
    {
        char* Sb  = SM;           // 7168: 64 rows x 112 S-bytes
        char* LUT = SM + 7168;    // 4096: byte -> 8 bf16 {0,1}
        char* Bsm = SM + 11264;   // 2 x 16384: 128 h-rows x 128 B (BK=64)
        int r0 = (bx >> 1) * 64, c0 = (bx & 1) * 128;
        int wc2 = wid;            // each wave: 64 rows x 32 cols
        const int NT = (npavSh + 63) >> 6;  // dynamic compact K-tiles (typ. ~7)

        {   // LUT
            unsigned e = tid;
            uint4 q;
            q.x = ((e & 1) ? 0x3F80u : 0u) | ((e & 2) ? 0x3F800000u : 0u);
            q.y = ((e & 4) ? 0x3F80u : 0u) | ((e & 8) ? 0x3F800000u : 0u);
            q.z = ((e & 16) ? 0x3F80u : 0u) | ((e & 32) ? 0x3F800000u : 0u);
            q.w = ((e & 64) ? 0x3F80u : 0u) | ((e & 128) ? 0x3F800000u : 0u);
            *(uint4*)(LUT + e * 16) = q;
        }
        {   // stage Sb: 448 16B chunks (contiguous)
            gload16(sbytes + (size_t)r0 * SBS + (size_t)tid * 16, Sb + tid * 16);
            int cch = 256 + tid;
            if (cch < 448) gload16(sbytes + (size_t)r0 * SBS + (size_t)cch * 16, Sb + cch * 16);
        }
        auto stageB = [&](int bi, int kb) {
#pragma unroll
            for (int rep = 0; rep < 4; ++rep) {
                int X = (rep * 256 + tid) * 16;
                int L = X ^ (((X >> 7) & 7) << 4);  // involutive swizzle
                int row = L >> 7, koff = L & 127;
                gload16((const char*)EWt + ((size_t)(c0 + row) * NPADJ + kb) * 2 + koff,
                        Bsm + bi * 16384 + X);
            }
        };
        if (NT > 0) stageB(0, 0);

        f4v acc[4][2];
#pragma unroll
        for (int m = 0; m < 4; ++m)
#pragma unroll
            for (int n = 0; n < 2; ++n) acc[m][n] = (f4v)0.0f;
        __syncthreads();

        for (int t = 0; t < NT; ++t) {
            int cur = t & 1;
            if (t + 1 < NT) stageB(cur ^ 1, (t + 1) * 64);
            int kg = lane >> 4;
            u64 sq[4];
#pragma unroll
            for (int m = 0; m < 4; ++m) {
                int row = m * 16 + (lane & 15);
                sq[m] = *(const u64*)(Sb + row * SBS + t * 8);  // 8 S-bytes, aligned
            }
#pragma unroll
            for (int ks = 0; ks < 2; ++ks) {
                s8v a[4], b[2];
#pragma unroll
                for (int m = 0; m < 4; ++m) {
                    unsigned by = (unsigned)(sq[m] >> (ks * 32 + kg * 8)) & 0xffu;
                    a[m] = *(const s8v*)(LUT + by * 16);
                }
#pragma unroll
                for (int n = 0; n < 2; ++n) {
                    int row = wc2 * 32 + n * 16 + (lane & 15);
                    b[n] = *(const s8v*)(Bsm + cur * 16384 + ((row * 128 + ks * 64 + kg * 16) ^ ((row & 7) << 4)));
                }
#pragma unroll
                for (int m = 0; m < 4; ++m)
#pragma unroll
                    for (int n = 0; n < 2; ++n)
                        acc[m][n] = __builtin_amdgcn_mfma_f32_16x16x32_bf16(a[m], b[n], acc[m][n], 0, 0, 0);
            }
            __syncthreads();
        }
        // epilogue: scale by 1/cnt, add bias
#pragma unroll
        for (int m = 0; m < 4; ++m) {
            int rbase = r0 + m * 16 + (lane >> 4) * 4;
            float rc[4];
#pragma unroll
            for (int r4 = 0; r4 < 4; ++r4) rc[r4] = cntrcp[rbase + r4];
#pragma unroll
            for (int n = 0; n < 2; ++n) {
                int col = c0 + wc2 * 32 + n * 16 + (lane & 15);
                float bv = bias[col];
#pragma unroll
                for (int r4 = 0; r4 < 4; ++r4)
                    out[(size_t)(rbase + r4) * HH + col] = acc[m][n][r4] * rc[r4] + bv;
            }
        }
    }
}

extern "C" void kernel_launch(void* const* d_in, const int* in_sizes, int n_in,
                              void* d_out, int out_size, void* d_ws, size_t ws_size,
                              hipStream_t stream) {
    const int*   sm   = (const int*)d_in[0];
    const float* E    = (const float*)d_in[1];
    const int*   pa   = (const int*)d_in[2];
    const float* W    = (const float*)d_in[3];
    const float* bias = (const float*)d_in[4];
    float* out = (float*)d_out;

    char* ws = (char*)d_ws;
    float*         cntrcp = (float*)(ws + 0);               // 65536 B
    u16*           EWt    = (u16*)(ws + 65536);             // 458752 B
    unsigned char* sbytes = (unsigned char*)(ws + 524288);  // 1835008 B

    void* args[] = { (void*)&sm, (void*)&E, (void*)&pa, (void*)&W, (void*)&EWt,
                     (void*)&sbytes, (void*)&cntrcp, (void*)&bias, (void*)&out };
    hipLaunchCooperativeKernel((void*)k_all, dim3(GRID), dim3(256), args, 0, stream);
}

// Round 7
// 99.314 us; speedup vs baseline: 2.2411x; 2.2411x over previous
//
#include <hip/hip_runtime.h>
#include <hip/hip_bf16.h>

// TextualKnowledgeInjector  B=64 T=256 F=40 D=768 H=256
// out[r,h] = (sum_{p avail, both present} dot(E[i_p,j_p,:],W[h,:])) / max(cnt_r,1) + bias[h]
// Two fused launches (reverted from coop-merge: grid.sync cost >100us, R6):
//  k_front: blocks 0..55  : GEMM1  EWt[h][p] = W x E_pairs^T (256x896, K=768),
//                           fp32 inputs reg-staged + converted to bf16 inline.
//           blocks 56..311: per-row S-bit bytes + 1/cnt (pair masks built in LDS).
//  k_gemm2: out = S(16384xK) x EWt^T(Kx256), K=896, S from bytes via LDS LUT.

#define FF 40
#define DD 768
#define HH 256
#define NPADJ 896
#define NPREAL 780
#define NROWS 16384
#define SBS 112        // NPADJ/8 bytes per row
#define G1B 56         // 4 h-tiles x 14 p-tiles

typedef short s8v __attribute__((ext_vector_type(8)));
typedef float f4v __attribute__((ext_vector_type(4)));
typedef unsigned short u16;

__device__ __forceinline__ void gload16(const void* g, void* l) {
    __builtin_amdgcn_global_load_lds(
        (const __attribute__((address_space(1))) unsigned int*)g,
        (__attribute__((address_space(3))) unsigned int*)l, 16, 0, 0);
}
__device__ __forceinline__ u16 f2b(float f) {
    __hip_bfloat16 h = __float2bfloat16(f);
    return *(u16*)&h;
}
__device__ __forceinline__ unsigned pk2(float x, float y) {
    return (unsigned)f2b(x) | ((unsigned)f2b(y) << 16);
}
__device__ __forceinline__ int pair_erow(int p) {  // triangular p -> E row i*FF+j
    if (p >= NPREAL) return 0;                     // pad rows: finite garbage, S=0 masks
    int i = 0, base = 0;
    while (base + (FF - 1 - i) <= p) { base += FF - 1 - i; ++i; }
    int j = i + 1 + (p - base);
    return i * FF + j;
}

// ================= kernel 1: gemm1 + mask =================
__global__ __launch_bounds__(256) void k_front(const int* __restrict__ sm,
                                               const float* __restrict__ E,
                                               const int* __restrict__ pa,
                                               const float* __restrict__ W,
                                               u16* __restrict__ EWt,
                                               unsigned char* __restrict__ sbytes,
                                               float* __restrict__ cntrcp) {
    __shared__ __align__(16) char As[2][8192];
    __shared__ __align__(16) char Bs[2][8192];
    __shared__ unsigned long long pmT[8][SBS];
    int tid = threadIdx.x;

    if (blockIdx.x < G1B) {
        // ---- GEMM1: 64x64 tile over (h, p), K=768, BK=64 ----
        int bx = blockIdx.x / 14, by = blockIdx.x % 14;
        int r0 = bx * 64, c0 = by * 64;
        int lane = tid & 63, wid = tid >> 6;
        int wr = wid >> 1, wc = wid & 1;

        // staging slots: 4 reps; slot = tid + 256*rep; row = slot>>4, kq = slot&15 (4 f32)
        int sOff[4];
        const float* aSrc[4];
        const float* bSrc[4];
#pragma unroll
        for (int r = 0; r < 4; ++r) {
            int slot = tid + 256 * r;
            int row = slot >> 4, kq = slot & 15;
            sOff[r] = (row * 128 + kq * 8) ^ ((row & 7) << 4);
            aSrc[r] = W + (size_t)(r0 + row) * DD + kq * 4;
            bSrc[r] = E + (size_t)pair_erow(c0 + row) * DD + kq * 4;
        }
        f4v acc[2][2];
#pragma unroll
        for (int m = 0; m < 2; ++m)
#pragma unroll
            for (int n = 0; n < 2; ++n) acc[m][n] = (f4v)0.0f;

        float4 ra[4], rb[4];
#pragma unroll
        for (int r = 0; r < 4; ++r) { ra[r] = *(const float4*)aSrc[r]; rb[r] = *(const float4*)bSrc[r]; }
#pragma unroll
        for (int r = 0; r < 4; ++r) {
            *(uint2*)(As[0] + sOff[r]) = make_uint2(pk2(ra[r].x, ra[r].y), pk2(ra[r].z, ra[r].w));
            *(uint2*)(Bs[0] + sOff[r]) = make_uint2(pk2(rb[r].x, rb[r].y), pk2(rb[r].z, rb[r].w));
        }
        __syncthreads();

        const int NT = DD / 64;  // 12
        for (int t = 0; t < NT; ++t) {
            int cur = t & 1;
            if (t + 1 < NT) {
                int kb = (t + 1) * 64;
#pragma unroll
                for (int r = 0; r < 4; ++r) {
                    ra[r] = *(const float4*)(aSrc[r] + kb);
                    rb[r] = *(const float4*)(bSrc[r] + kb);
                }
            }
            int kg16 = (lane >> 4) * 16;
#pragma unroll
            for (int ks = 0; ks < 2; ++ks) {
                s8v a[2], b[2];
#pragma unroll
                for (int m = 0; m < 2; ++m) {
                    int row = wr * 32 + m * 16 + (lane & 15);
                    a[m] = *(const s8v*)(As[cur] + ((row * 128 + ks * 64 + kg16) ^ ((row & 7) << 4)));
                }
#pragma unroll
                for (int n = 0; n < 2; ++n) {
                    int row = wc * 32 + n * 16 + (lane & 15);
                    b[n] = *(const s8v*)(Bs[cur] + ((row * 128 + ks * 64 + kg16) ^ ((row & 7) << 4)));
                }
#pragma unroll
                for (int m = 0; m < 2; ++m)
#pragma unroll
                    for (int n = 0; n < 2; ++n)
                        acc[m][n] = __builtin_amdgcn_mfma_f32_16x16x32_bf16(a[m], b[n], acc[m][n], 0, 0, 0);
            }
            if (t + 1 < NT) {
                int nb = cur ^ 1;
#pragma unroll
                for (int r = 0; r < 4; ++r) {
                    *(uint2*)(As[nb] + sOff[r]) = make_uint2(pk2(ra[r].x, ra[r].y), pk2(ra[r].z, ra[r].w));
                    *(uint2*)(Bs[nb] + sOff[r]) = make_uint2(pk2(rb[r].x, rb[r].y), pk2(rb[r].z, rb[r].w));
                }
            }
            __syncthreads();
        }
#pragma unroll
        for (int m = 0; m < 2; ++m)
#pragma unroll
            for (int n = 0; n < 2; ++n) {
                int colp = c0 + wc * 32 + n * 16 + (lane & 15);
#pragma unroll
                for (int r = 0; r < 4; ++r) {
                    int rowh = r0 + wr * 32 + m * 16 + (lane >> 4) * 4 + r;
                    EWt[(size_t)rowh * NPADJ + colp] = f2b(acc[m][n][r]);
                }
            }
    } else {
        // ---- mask: 64 rows per block ----
        int mb = blockIdx.x - G1B;
        int r0 = mb * 64;
#pragma unroll
        for (int rep = 0; rep < 4; ++rep) {
            int p = rep * 256 + tid;
            if (p < NPADJ) {
                unsigned long long q = ~0ull;  // never satisfied by 40-bit mask
                if (p < NPREAL) {
                    int i = 0, base = 0;
                    while (base + (FF - 1 - i) <= p) { base += FF - 1 - i; ++i; }
                    int j = i + 1 + (p - base);
                    if (pa[i * FF + j] != 0) q = (1ull << i) | (1ull << j);
                }
                pmT[p & 7][p >> 3] = q;  // transposed: lanes read consecutive b -> 2-way (free)
            }
        }
        __syncthreads();
        int lane = tid & 63, wid = tid >> 6;
        int v = (lane < FF) ? sm[(size_t)(r0 + wid * 16) * FF + lane] : 0;
        for (int rr = 0; rr < 16; ++rr) {
            int row = r0 + wid * 16 + rr;
            int vnext = (rr + 1 < 16 && lane < FF) ? sm[(size_t)(row + 1) * FF + lane] : 0;
            unsigned long long mask = __ballot(v != 0);
            int c = 0;
#pragma unroll
            for (int rep = 0; rep < 2; ++rep) {
                int b = lane + rep * 64;
                if (b < SBS) {
                    unsigned bits = 0;
#pragma unroll
                    for (int e = 0; e < 8; ++e) {
                        unsigned long long q = pmT[e][b];
                        bits |= ((mask & q) == q) ? (1u << e) : 0u;
                    }
                    sbytes[(size_t)row * SBS + b] = (unsigned char)bits;
                    c += __popc(bits);
                }
            }
#pragma unroll
            for (int o = 32; o; o >>= 1) c += __shfl_xor(c, o, 64);
            if (lane == 0) cntrcp[row] = 1.0f / (float)(c > 0 ? c : 1);
            v = vnext;
        }
    }
}

// ================= kernel 2: out = S x EWt^T =================
__global__ __launch_bounds__(256) void k_gemm2(const unsigned char* __restrict__ sbytes,
                                               const u16* __restrict__ EWt,
                                               const float* __restrict__ cntrcp,
                                               const float* __restrict__ bias,
                                               float* __restrict__ out) {
    __shared__ __align__(16) char Sb[7168];       // 64 rows x 112 bytes
    __shared__ __align__(16) char LUT[4096];      // byte -> 8 bf16 {0,1}
    __shared__ __align__(16) char Bsm[2][16384];  // 128 h-rows x 128 B (BK=64)
    int tid = threadIdx.x, lane = tid & 63, wid = tid >> 6;
    int r0 = blockIdx.x * 64, c0 = blockIdx.y * 128;
    int wc = wid;  // each wave: 64 rows x 32 cols

    {   // LUT: entry e, elem i = bit i of e as bf16 1.0/0.0
        unsigned e = tid;
        uint4 q;
        q.x = ((e & 1) ? 0x3F80u : 0u) | ((e & 2) ? 0x3F800000u : 0u);
        q.y = ((e & 4) ? 0x3F80u : 0u) | ((e & 8) ? 0x3F800000u : 0u);
        q.z = ((e & 16) ? 0x3F80u : 0u) | ((e & 32) ? 0x3F800000u : 0u);
        q.w = ((e & 64) ? 0x3F80u : 0u) | ((e & 128) ? 0x3F800000u : 0u);
        *(uint4*)(LUT + e * 16) = q;
    }
    {   // stage Sb: 448 16B chunks (contiguous)
        gload16(sbytes + (size_t)r0 * SBS + (size_t)tid * 16, Sb + tid * 16);
        int cch = 256 + tid;
        if (cch < 448) gload16(sbytes + (size_t)r0 * SBS + (size_t)cch * 16, Sb + cch * 16);
    }
    auto stageB = [&](int bi, int kb) {
#pragma unroll
        for (int rep = 0; rep < 4; ++rep) {
            int X = (rep * 256 + tid) * 16;
            int L = X ^ (((X >> 7) & 7) << 4);  // involutive: bits4-6 <- row bits (>=7)
            int row = L >> 7, koff = L & 127;
            gload16((const char*)EWt + ((size_t)(c0 + row) * NPADJ + kb) * 2 + koff, Bsm[bi] + X);
        }
    };
    stageB(0, 0);

    f4v acc[4][2];
#pragma unroll
    for (int m = 0; m < 4; ++m)
#pragma unroll
        for (int n = 0; n < 2; ++n) acc[m][n] = (f4v)0.0f;
    __syncthreads();

    const int NT = NPADJ / 64;  // 14
    for (int t = 0; t < NT; ++t) {
        int cur = t & 1;
        if (t + 1 < NT) stageB(cur ^ 1, (t + 1) * 64);
        int kg = lane >> 4;
#pragma unroll
        for (int ks = 0; ks < 2; ++ks) {
            s8v a[4], b[2];
#pragma unroll
            for (int m = 0; m < 4; ++m) {
                int row = m * 16 + (lane & 15);
                unsigned by = *(const unsigned char*)(Sb + row * SBS + t * 8 + ks * 4 + kg);
                a[m] = *(const s8v*)(LUT + by * 16);
            }
#pragma unroll
            for (int n = 0; n < 2; ++n) {
                int row = wc * 32 + n * 16 + (lane & 15);
                b[n] = *(const s8v*)(Bsm[cur] + ((row * 128 + ks * 64 + kg * 16) ^ ((row & 7) << 4)));
            }
#pragma unroll
            for (int m = 0; m < 4; ++m)
#pragma unroll
                for (int n = 0; n < 2; ++n)
                    acc[m][n] = __builtin_amdgcn_mfma_f32_16x16x32_bf16(a[m], b[n], acc[m][n], 0, 0, 0);
        }
        __syncthreads();
    }
    // epilogue: scale by 1/cnt, add bias
#pragma unroll
    for (int m = 0; m < 4; ++m) {
        int rbase = r0 + m * 16 + (lane >> 4) * 4;
        float rc[4];
#pragma unroll
        for (int r = 0; r < 4; ++r) rc[r] = cntrcp[rbase + r];
#pragma unroll
        for (int n = 0; n < 2; ++n) {
            int col = c0 + wc * 32 + n * 16 + (lane & 15);
            float bv = bias[col];
#pragma unroll
            for (int r = 0; r < 4; ++r)
                out[(size_t)(rbase + r) * HH + col] = acc[m][n][r] * rc[r] + bv;
        }
    }
}

extern "C" void kernel_launch(void* const* d_in, const int* in_sizes, int n_in,
                              void* d_out, int out_size, void* d_ws, size_t ws_size,
                              hipStream_t stream) {
    const int*   sm   = (const int*)d_in[0];
    const float* E    = (const float*)d_in[1];
    const int*   pa   = (const int*)d_in[2];
    const float* W    = (const float*)d_in[3];
    const float* bias = (const float*)d_in[4];
    float* out = (float*)d_out;

    char* ws = (char*)d_ws;
    float*         cntrcp = (float*)(ws + 0);           // 65536 B
    u16*           EWt    = (u16*)(ws + 65536);         // 458752 B
    unsigned char* sbytes = (unsigned char*)(ws + 524288);  // 1835008 B

    hipLaunchKernelGGL(k_front, dim3(G1B + NROWS / 64), dim3(256), 0, stream,
                       sm, E, pa, W, EWt, sbytes, cntrcp);
    hipLaunchKernelGGL(k_gemm2, dim3(NROWS / 64, 2), dim3(256), 0, stream,
                       sbytes, EWt, cntrcp, bias, out);
}